// Round 3
// baseline (334.571 us; speedup 1.0000x reference)
//
#include <hip/hip_runtime.h>

typedef _Float16 f16;
typedef _Float16 f16x8 __attribute__((ext_vector_type(8)));
typedef _Float16 f16x4 __attribute__((ext_vector_type(4)));
typedef float    f32x4 __attribute__((ext_vector_type(4)));

#define MFMA16(a, b, c) __builtin_amdgcn_mfma_f32_16x16x32_f16((a), (b), (c), 0, 0, 0)

constexpr int T = 64;    // sequence length
constexpr int C = 384;   // n_embd
constexpr int H = 64;    // head size
constexpr float SCALE = 3.26598632371090f;  // 64 * 384^-0.5

// ---------------------------------------------------------------------------
// Pack Wk,Wq,Wv (fp32 [64][384]) into f16 MFMA-fragment order in d_ws.
// Layout: Wp[((wi*12 + kt)*4 + ht)*512 + lane*8 + j]
//   = W_wi[16*ht + (lane&15)][32*kt + 8*(lane>>4) + j]
// Simultaneously the A-frag (m=lane&15,k=quad*8+j) and B-frag layout for
// 16x16x32 MFMA.
// ---------------------------------------------------------------------------
__global__ void pack_w(const float* __restrict__ Wk, const float* __restrict__ Wq,
                       const float* __restrict__ Wv, f16* __restrict__ Wp) {
  int tid = blockIdx.x * blockDim.x + threadIdx.x;
  if (tid >= 3 * 12 * 4 * 64) return;
  int lane = tid & 63;
  int tile = tid >> 6;          // (wi*12 + kt)*4 + ht
  int ht = tile & 3;
  int kt = (tile >> 2) % 12;
  int wi = tile / 48;
  const float* W = (wi == 0) ? Wk : ((wi == 1) ? Wq : Wv);
  int h = 16 * ht + (lane & 15);
  int c = 32 * kt + 8 * (lane >> 4);
  const float* src = W + h * C + c;
  f16x8 v;
#pragma unroll
  for (int j = 0; j < 8; ++j) v[j] = (f16)src[j];
  *(f16x8*)(Wp + (size_t)tile * 512 + lane * 8) = v;
}

// ---------------------------------------------------------------------------
// Fused head kernel: one block per batch, 4 waves.
// R3: phase-1 work split by (matrix,ht) combo instead of t-strip. Wave w
// computes combos [3w, 3w+3) over ALL 64 rows: per kt only 3 Wp L2 loads
// (was 12), each fragment feeding 4 MFMAs. Wp L2 traffic /4; x re-reads
// within the block hit L1. Phases 2-4 (attention, per-t-strip) unchanged.
// ---------------------------------------------------------------------------
__global__ __launch_bounds__(256, 4) void head_fused(
    const float* __restrict__ x, const f16* __restrict__ Wp,
    float* __restrict__ out) {
  // pitch 72 f16 = 36 dwords; 36 % 32 = 4 -> <=2-way LDS bank aliasing (free)
  __shared__ f16 qp_lds[64][72];  // phases 1-2: q[t][h]; phases 3-4: P[t][s]
  __shared__ f16 k_lds[64][72];   // k[t][h]
  __shared__ f16 vT_lds[64][72];  // v^T[h][t]

  const int b = blockIdx.x;
  const int tid = threadIdx.x;
  const int w = tid >> 6;       // wave 0..3
  const int lane = tid & 63;
  const int l15 = lane & 15;
  const int g = lane >> 4;      // quad 0..3
  const int t_ = 16 * w + l15;  // this lane's t for phases 2-4

  const f32x4 vzero = {0.0f, 0.0f, 0.0f, 0.0f};
  // acc[c][tt]: combo c = 3w+c (c<3), t-tile tt (16 rows each)
  f32x4 acc[3][4];
#pragma unroll
  for (int c = 0; c < 3; ++c)
#pragma unroll
    for (int tt = 0; tt < 4; ++tt) acc[c][tt] = vzero;

  // Per-combo Wp base: combo = 3w+c -> matrix m = combo>>2, ht = combo&3.
  const f16* wp_base[3];
  bool isV[3];
#pragma unroll
  for (int c = 0; c < 3; ++c) {
    int combo = 3 * w + c;
    int m = combo >> 2;
    int ht = combo & 3;
    wp_base[c] = Wp + (size_t)(m * 48 + ht) * 512 + lane * 8;
    isV[c] = (combo >= 8);
  }

  const float* xbase = x + (size_t)b * T * C;

  // ---- Phase 1: projections over all 64 rows, 3 combos per wave.
#pragma unroll
  for (int kt = 0; kt < 12; ++kt) {
    // 4 t-tiles of x: lane (g,l15) reads row 16tt+l15, cols kt*32+g*8 .. +16
    f16x8 xf[4];
#pragma unroll
    for (int tt = 0; tt < 4; ++tt) {
      const float* xr = xbase + (size_t)(16 * tt + l15) * C + kt * 32 + g * 8;
      f32x4 a0 = *(const f32x4*)(xr);
      f32x4 a1 = *(const f32x4*)(xr + 4);
#pragma unroll
      for (int j = 0; j < 4; ++j) { xf[tt][j] = (f16)a0[j]; xf[tt][4 + j] = (f16)a1[j]; }
    }
#pragma unroll
    for (int c = 0; c < 3; ++c) {
      f16x8 wf = *(const f16x8*)(wp_base[c] + kt * 2048);
      if (!isV[c]) {  // K or Q: D[h][t] tiles (W as A, x as B) — wave-uniform
#pragma unroll
        for (int tt = 0; tt < 4; ++tt) acc[c][tt] = MFMA16(wf, xf[tt], acc[c][tt]);
      } else {        // V: D[t][h] tiles (x as A, W as B)
#pragma unroll
        for (int tt = 0; tt < 4; ++tt) acc[c][tt] = MFMA16(xf[tt], wf, acc[c][tt]);
      }
    }
  }

  // ---- Phase-1 epilogue: write q/k/vT to LDS, D-layout, b64 per tile.
#pragma unroll
  for (int c = 0; c < 3; ++c) {
    int combo = 3 * w + c;
    int m = combo >> 2;
    int ht = combo & 3;
#pragma unroll
    for (int tt = 0; tt < 4; ++tt) {
      f16x4 pd;
#pragma unroll
      for (int r = 0; r < 4; ++r) pd[r] = (f16)acc[c][tt][r];
      if (m == 0) {        // K: col=t (16tt+l15), row=h (16ht+4g+r)
        *(f16x4*)&k_lds[16 * tt + l15][16 * ht + 4 * g] = pd;
      } else if (m == 1) { // Q
        *(f16x4*)&qp_lds[16 * tt + l15][16 * ht + 4 * g] = pd;
      } else {             // V: col=h (16ht+l15), row=t (16tt+4g+r)
        *(f16x4*)&vT_lds[16 * ht + l15][16 * tt + 4 * g] = pd;
      }
    }
  }
  __syncthreads();

  // ---- Phase 2: S^T = k.q^T  (lane holds column t_ of S, 16 s-entries)
  f32x4 accs[4];
#pragma unroll
  for (int i = 0; i < 4; ++i) accs[i] = vzero;
#pragma unroll
  for (int kt = 0; kt < 2; ++kt) {
    f16x8 qf = *(const f16x8*)&qp_lds[t_][32 * kt + 8 * g];
#pragma unroll
    for (int mt = 0; mt < 4; ++mt) {
      f16x8 kf = *(const f16x8*)&k_lds[16 * mt + l15][32 * kt + 8 * g];
      accs[mt] = MFMA16(kf, qf, accs[mt]);  // D[s][t]: s = 16mt+4g+r, t = t_
    }
  }

  // ---- Phase 3: causal mask + softmax over s (per column t_, fp32)
  float e[16];
  float mx = -__builtin_inff();
#pragma unroll
  for (int mt = 0; mt < 4; ++mt) {
#pragma unroll
    for (int r = 0; r < 4; ++r) {
      int s = 16 * mt + 4 * g + r;
      float lv = accs[mt][r] * SCALE;
      lv = (s <= t_) ? lv : -__builtin_inff();
      e[mt * 4 + r] = lv;
      mx = fmaxf(mx, lv);
    }
  }
  mx = fmaxf(mx, __shfl_xor(mx, 16));
  mx = fmaxf(mx, __shfl_xor(mx, 32));
  float sm = 0.0f;
#pragma unroll
  for (int i = 0; i < 16; ++i) { e[i] = __expf(e[i] - mx); sm += e[i]; }
  sm += __shfl_xor(sm, 16);
  sm += __shfl_xor(sm, 32);
  const float inv = 1.0f / sm;
  // P overwrites qp_lds rows [16w,16w+16): wave-private rows; all other
  // waves' post-barrier qp_lds reads are own-row only. No barrier needed.
#pragma unroll
  for (int mt = 0; mt < 4; ++mt) {
    f16x4 pp;
#pragma unroll
    for (int r = 0; r < 4; ++r) pp[r] = (f16)(e[mt * 4 + r] * inv);
    *(f16x4*)&qp_lds[t_][16 * mt + 4 * g] = pp;  // P[t][s], s = 16mt+4g+r
  }

  // ---- Phase 4: out^T = v^T . P^T  (A = vT, B-frag from P[t][s])
  f32x4 acco[4];
#pragma unroll
  for (int i = 0; i < 4; ++i) acco[i] = vzero;
#pragma unroll
  for (int kt = 0; kt < 2; ++kt) {
    f16x8 pf = *(const f16x8*)&qp_lds[t_][32 * kt + 8 * g];
#pragma unroll
    for (int mt = 0; mt < 4; ++mt) {
      f16x8 vf = *(const f16x8*)&vT_lds[16 * mt + l15][32 * kt + 8 * g];
      acco[mt] = MFMA16(vf, pf, acco[mt]);  // D[h][t]: h = 16mt+4g+r, t = t_
    }
  }

  // ---- store: out[b][t][h] fp32, 4 consecutive h per reg quad -> float4
  float* orow = out + ((size_t)b * T + t_) * H;
#pragma unroll
  for (int mt = 0; mt < 4; ++mt) {
    *(f32x4*)(orow + 16 * mt + 4 * g) = acco[mt];
  }
}

extern "C" void kernel_launch(void* const* d_in, const int* in_sizes, int n_in,
                              void* d_out, int out_size, void* d_ws, size_t ws_size,
                              hipStream_t stream) {
  const float* x  = (const float*)d_in[0];
  const float* Wk = (const float*)d_in[1];
  const float* Wq = (const float*)d_in[2];
  const float* Wv = (const float*)d_in[3];
  float* out = (float*)d_out;
  f16* Wp = (f16*)d_ws;  // 3*12*4*64*8 f16 = 147456 B

  // Re-pack every launch: d_ws is re-poisoned before each timed call.
  pack_w<<<36, 256, 0, stream>>>(Wk, Wq, Wv, Wp);
  head_fused<<<2048, 256, 0, stream>>>(x, Wp, out);
}

// Round 4
// 304.914 us; speedup vs baseline: 1.0973x; 1.0973x over previous
//
#include <hip/hip_runtime.h>

typedef _Float16 f16;
typedef _Float16 f16x8 __attribute__((ext_vector_type(8)));
typedef _Float16 f16x4 __attribute__((ext_vector_type(4)));
typedef float    f32x4 __attribute__((ext_vector_type(4)));

#define MFMA16(a, b, c) __builtin_amdgcn_mfma_f32_16x16x32_f16((a), (b), (c), 0, 0, 0)

constexpr int T = 64;    // sequence length
constexpr int C = 384;   // n_embd
constexpr int H = 64;    // head size
constexpr float SCALE = 3.26598632371090f;  // 64 * 384^-0.5

// async global->LDS, 16B per lane; LDS dest = wave-uniform base + lane*16
__device__ __forceinline__ void load_lds16(const float* g, float* l) {
  __builtin_amdgcn_global_load_lds(
      (const __attribute__((address_space(1))) void*)g,
      (__attribute__((address_space(3))) void*)l, 16, 0, 0);
}

// ---------------------------------------------------------------------------
// Pack Wk,Wq,Wv (fp32 [64][384]) into f16 MFMA-fragment order in d_ws.
// Wp[((wi*12 + kt)*4 + ht)*512 + lane*8 + j]
//   = W_wi[16*ht + (lane&15)][32*kt + 8*(lane>>4) + j]
// ---------------------------------------------------------------------------
__global__ void pack_w(const float* __restrict__ Wk, const float* __restrict__ Wq,
                       const float* __restrict__ Wv, f16* __restrict__ Wp) {
  int tid = blockIdx.x * blockDim.x + threadIdx.x;
  if (tid >= 3 * 12 * 4 * 64) return;
  int lane = tid & 63;
  int tile = tid >> 6;          // (wi*12 + kt)*4 + ht
  int ht = tile & 3;
  int kt = (tile >> 2) % 12;
  int wi = tile / 48;
  const float* W = (wi == 0) ? Wk : ((wi == 1) ? Wq : Wv);
  int h = 16 * ht + (lane & 15);
  int c = 32 * kt + 8 * (lane >> 4);
  const float* src = W + h * C + c;
  f16x8 v;
#pragma unroll
  for (int j = 0; j < 8; ++j) v[j] = (f16)src[j];
  *(f16x8*)(Wp + (size_t)tile * 512 + lane * 8) = v;
}

// ---------------------------------------------------------------------------
// Fused head kernel: one block per batch, 4 waves.
// R4: x staged via async global_load_lds (zero payload VGPRs -> full-chunk
// MLP), chunk = one kt (64r x 32c fp32, 8 KB), double-buffered. LDS chunk
// layout is fragment-interleaved: xc[buf][(tt*2+half)*256 + lane*4 + j]
//   = x[16tt + (lane&15)][kt*32 + (lane>>4)*8 + half*4 + j]
// -> staging is lane-contiguous (HW constraint), fragment ds_read_b128 has
// lane-stride 16B (conflict-free). Wp frags register-prefetched 1 kt ahead.
// Phase-1 combo split (R3) and phases 2-4 unchanged.
// ---------------------------------------------------------------------------
__global__ __launch_bounds__(256, 3) void head_fused(
    const float* __restrict__ x, const f16* __restrict__ Wp,
    float* __restrict__ out) {
  __shared__ float xc[2][2048];   // 2 x 8 KB staging buffers
  // pitch 72 f16 = 36 dwords; 36 % 32 = 4 -> <=2-way LDS bank aliasing (free)
  __shared__ f16 qp_lds[64][72];  // phases 1-2: q[t][h]; phases 3-4: P[t][s]
  __shared__ f16 k_lds[64][72];   // k[t][h]
  __shared__ f16 vT_lds[64][72];  // v^T[h][t]

  const int b = blockIdx.x;
  const int tid = threadIdx.x;
  const int w = tid >> 6;       // wave 0..3
  const int lane = tid & 63;
  const int l15 = lane & 15;
  const int g = lane >> 4;      // quad 0..3
  const int t_ = 16 * w + l15;  // this lane's t for phases 2-4

  const f32x4 vzero = {0.0f, 0.0f, 0.0f, 0.0f};
  f32x4 acc[3][4];              // combo c = 3w+c, t-tile tt
#pragma unroll
  for (int c = 0; c < 3; ++c)
#pragma unroll
    for (int tt = 0; tt < 4; ++tt) acc[c][tt] = vzero;

  const f16* wp_base[3];
  bool isV[3];
#pragma unroll
  for (int c = 0; c < 3; ++c) {
    int combo = 3 * w + c;
    int m = combo >> 2;
    int ht = combo & 3;
    wp_base[c] = Wp + (size_t)(m * 48 + ht) * 512 + lane * 8;
    isV[c] = (combo >= 8);
  }

  const float* xbase = x + (size_t)b * T * C;
  // Wave w stages rows [16w,16w+16): lane's own global element for tt=w.
  // Instr j=2w+half covers LDS [j*1024,(j+1)*1024) = all 64 lanes x 16B.
  const float* gsrc = xbase + (size_t)(16 * w + l15) * C + g * 8;

  // ---- preload: stage chunk 0, prefetch Wp(kt=0) frags
  load_lds16(gsrc + 0 * 32 + 0, &xc[0][(2 * w + 0) * 256]);
  load_lds16(gsrc + 0 * 32 + 4, &xc[0][(2 * w + 1) * 256]);
  f16x8 wpc[3], wpn[3];
#pragma unroll
  for (int c = 0; c < 3; ++c) wpc[c] = *(const f16x8*)(wp_base[c]);

  // ---- Phase 1: 12 chunks, double-buffered async staging
#pragma unroll 2
  for (int kt = 0; kt < 12; ++kt) {
    const int cur = kt & 1;
    if (kt + 1 < 12) {
      load_lds16(gsrc + (kt + 1) * 32 + 0, &xc[cur ^ 1][(2 * w + 0) * 256]);
      load_lds16(gsrc + (kt + 1) * 32 + 4, &xc[cur ^ 1][(2 * w + 1) * 256]);
#pragma unroll
      for (int c = 0; c < 3; ++c)
        wpn[c] = *(const f16x8*)(wp_base[c] + (size_t)(kt + 1) * 2048);
    }
    __builtin_amdgcn_s_waitcnt(0x0f70);  // vmcnt(0): stage of cur complete
    __syncthreads();                     // visible to all waves

    f16x8 xf[4];
#pragma unroll
    for (int tt = 0; tt < 4; ++tt) {
      f32x4 A0 = *(const f32x4*)&xc[cur][(2 * tt + 0) * 256 + lane * 4];
      f32x4 A1 = *(const f32x4*)&xc[cur][(2 * tt + 1) * 256 + lane * 4];
#pragma unroll
      for (int j = 0; j < 4; ++j) { xf[tt][j] = (f16)A0[j]; xf[tt][4 + j] = (f16)A1[j]; }
    }
#pragma unroll
    for (int c = 0; c < 3; ++c) {
      f16x8 wf = wpc[c];
      if (!isV[c]) {  // K or Q: D[h][t] (W as A, x as B)
#pragma unroll
        for (int tt = 0; tt < 4; ++tt) acc[c][tt] = MFMA16(wf, xf[tt], acc[c][tt]);
      } else {        // V: D[t][h] (x as A, W as B)
#pragma unroll
        for (int tt = 0; tt < 4; ++tt) acc[c][tt] = MFMA16(xf[tt], wf, acc[c][tt]);
      }
      wpc[c] = wpn[c];
    }
    __syncthreads();  // all reads of cur done before it's restaged at kt+2
  }

  // ---- Phase-1 epilogue: write q/k/vT to LDS, D-layout, b64 per tile.
#pragma unroll
  for (int c = 0; c < 3; ++c) {
    int combo = 3 * w + c;
    int m = combo >> 2;
    int ht = combo & 3;
#pragma unroll
    for (int tt = 0; tt < 4; ++tt) {
      f16x4 pd;
#pragma unroll
      for (int r = 0; r < 4; ++r) pd[r] = (f16)acc[c][tt][r];
      if (m == 0) {        // K: col=t (16tt+l15), row=h (16ht+4g+r)
        *(f16x4*)&k_lds[16 * tt + l15][16 * ht + 4 * g] = pd;
      } else if (m == 1) { // Q
        *(f16x4*)&qp_lds[16 * tt + l15][16 * ht + 4 * g] = pd;
      } else {             // V: col=h (16ht+l15), row=t (16tt+4g+r)
        *(f16x4*)&vT_lds[16 * ht + l15][16 * tt + 4 * g] = pd;
      }
    }
  }
  __syncthreads();

  // ---- Phase 2: S^T = k.q^T  (lane holds column t_ of S, 16 s-entries)
  f32x4 accs[4];
#pragma unroll
  for (int i = 0; i < 4; ++i) accs[i] = vzero;
#pragma unroll
  for (int kt = 0; kt < 2; ++kt) {
    f16x8 qf = *(const f16x8*)&qp_lds[t_][32 * kt + 8 * g];
#pragma unroll
    for (int mt = 0; mt < 4; ++mt) {
      f16x8 kf = *(const f16x8*)&k_lds[16 * mt + l15][32 * kt + 8 * g];
      accs[mt] = MFMA16(kf, qf, accs[mt]);  // D[s][t]: s = 16mt+4g+r, t = t_
    }
  }

  // ---- Phase 3: causal mask + softmax over s (per column t_, fp32)
  float e[16];
  float mx = -__builtin_inff();
#pragma unroll
  for (int mt = 0; mt < 4; ++mt) {
#pragma unroll
    for (int r = 0; r < 4; ++r) {
      int s = 16 * mt + 4 * g + r;
      float lv = accs[mt][r] * SCALE;
      lv = (s <= t_) ? lv : -__builtin_inff();
      e[mt * 4 + r] = lv;
      mx = fmaxf(mx, lv);
    }
  }
  mx = fmaxf(mx, __shfl_xor(mx, 16));
  mx = fmaxf(mx, __shfl_xor(mx, 32));
  float sm = 0.0f;
#pragma unroll
  for (int i = 0; i < 16; ++i) { e[i] = __expf(e[i] - mx); sm += e[i]; }
  sm += __shfl_xor(sm, 16);
  sm += __shfl_xor(sm, 32);
  const float inv = 1.0f / sm;
  // P overwrites qp_lds rows [16w,16w+16): wave-private rows; all other
  // waves' post-barrier qp_lds reads are own-row only. No barrier needed.
#pragma unroll
  for (int mt = 0; mt < 4; ++mt) {
    f16x4 pp;
#pragma unroll
    for (int r = 0; r < 4; ++r) pp[r] = (f16)(e[mt * 4 + r] * inv);
    *(f16x4*)&qp_lds[t_][16 * mt + 4 * g] = pp;  // P[t][s], s = 16mt+4g+r
  }

  // ---- Phase 4: out^T = v^T . P^T  (A = vT, B-frag from P[t][s])
  f32x4 acco[4];
#pragma unroll
  for (int i = 0; i < 4; ++i) acco[i] = vzero;
#pragma unroll
  for (int kt = 0; kt < 2; ++kt) {
    f16x8 pf = *(const f16x8*)&qp_lds[t_][32 * kt + 8 * g];
#pragma unroll
    for (int mt = 0; mt < 4; ++mt) {
      f16x8 vf = *(const f16x8*)&vT_lds[16 * mt + l15][32 * kt + 8 * g];
      acco[mt] = MFMA16(vf, pf, acco[mt]);  // D[h][t]: h = 16mt+4g+r, t = t_
    }
  }

  // ---- store: out[b][t][h] fp32, 4 consecutive h per reg quad -> float4
  float* orow = out + ((size_t)b * T + t_) * H;
#pragma unroll
  for (int mt = 0; mt < 4; ++mt) {
    *(f32x4*)(orow + 16 * mt + 4 * g) = acco[mt];
  }
}

extern "C" void kernel_launch(void* const* d_in, const int* in_sizes, int n_in,
                              void* d_out, int out_size, void* d_ws, size_t ws_size,
                              hipStream_t stream) {
  const float* x  = (const float*)d_in[0];
  const float* Wk = (const float*)d_in[1];
  const float* Wq = (const float*)d_in[2];
  const float* Wv = (const float*)d_in[3];
  float* out = (float*)d_out;
  f16* Wp = (f16*)d_ws;  // 3*12*4*64*8 f16 = 147456 B

  // Re-pack every launch: d_ws is re-poisoned before each timed call.
  pack_w<<<36, 256, 0, stream>>>(Wk, Wq, Wv, Wp);
  head_fused<<<2048, 256, 0, stream>>>(x, Wp, out);
}